// Round 11
// baseline (753.275 us; speedup 1.0000x reference)
//
#include <hip/hip_runtime.h>
#include <hip/hip_bf16.h>
#include <stdint.h>

// WindowAttention (Swin, shifted): x[2048,49,512] f32 -> out[2048,49,512] f32
// Pipeline:
//   k_wprep: cast+transpose weights to bf16 [N][K]; q-cols pre-scaled by 32^-0.5; bias2
//   k_xcast: x f32 -> bf16 (into aout region, dead until attn writes it)
//   k_tabs : bias[h][64][64], mask[mw][64][64] f32 tables (pad rows/cols = -1e30)
//   k_gemm<0>: qkv = xb @ Wt^T + bias2     (bf16 out, 158 GF)
//   k_attn : block=window, 4 waves; swapped QK^T lane-local softmax (R6 version)
//   k_gemm<1>: out = aout @ Pt^T + proj_b  (f32 out, 53 GF)
// k_gemm: 128x128 tile, 4 waves, BK=64. A: LDS double-buffer via global_load_lds
// (T2 XOR-swizzle, counted vmcnt(12) -- tile-kt A landed, kt+1 A + kt B fly on).
// B: DIRECT global->VGPR from the L2-resident weight panel (no LDS staging --
// halves LDS traffic; LDS pipe was the binding resource at R10).
// T1 XCD-contiguous block swizzle, LDS-staged coalesced epilogue.

#define HEADS 16
#define NTOK  49
#define CH    512

typedef float  f32x4  __attribute__((ext_vector_type(4)));
typedef __bf16 bf16x8 __attribute__((ext_vector_type(8)));
typedef unsigned short u16;
typedef unsigned int   u32;

__device__ __forceinline__ u16 f2bf(float f) {
  return __builtin_bit_cast(u16, (__bf16)f);   // native v_cvt, RNE
}

__device__ __forceinline__ void gload16(const u16* g, u16* l) {
  __builtin_amdgcn_global_load_lds(
      (const __attribute__((address_space(1))) u32*)g,
      (__attribute__((address_space(3))) u32*)l, 16, 0, 0);
}

// ---------------- weight prep (+ q-scale folding) ----------------
__global__ __launch_bounds__(256) void k_wprep(const float* __restrict__ qkv_w,
                                               const float* __restrict__ proj_w,
                                               const float* __restrict__ qkv_b,
                                               u16* __restrict__ Wt, u16* __restrict__ Pt,
                                               float* __restrict__ bias2) {
  const float sc = 0.17677669529663687f;       // 32^-0.5
  int tid = blockIdx.x * 256 + threadIdx.x;
  const int T1 = 1536 * 512;
  if (tid < 1536) bias2[tid] = qkv_b[tid] * (tid < 512 ? sc : 1.f);
  if (tid < T1) {
    int n = tid >> 9, k = tid & 511;
    float v = qkv_w[k * 1536 + n];
    if (n < 512) v *= sc;
    Wt[tid] = f2bf(v);
  } else {
    int t2 = tid - T1;
    int n = t2 >> 9, k = t2 & 511;
    Pt[t2] = f2bf(proj_w[k * 512 + n]);
  }
}

// ---------------- x cast: f32 -> bf16, 8 elems/thread ----------------
__global__ __launch_bounds__(256) void k_xcast(const float* __restrict__ x,
                                               u16* __restrict__ xb) {
  int tid = blockIdx.x * 256 + threadIdx.x;
  const float4* xv = (const float4*)x;
  float4 a = xv[tid * 2], b = xv[tid * 2 + 1];
  u16 o[8] = {f2bf(a.x), f2bf(a.y), f2bf(a.z), f2bf(a.w),
              f2bf(b.x), f2bf(b.y), f2bf(b.z), f2bf(b.w)};
  ((int4*)xb)[tid] = *(const int4*)o;
}

// ---------------- bias/mask tables ([q][k] layout, pad = -1e30 in bias) ----------------
__global__ __launch_bounds__(256) void k_tabs(const float* __restrict__ bias_table,
                                              float* __restrict__ biasM,
                                              float* __restrict__ maskT) {
  int tid = blockIdx.x * 256 + threadIdx.x;
  if (tid < 16 * 4096) {
    int h = tid >> 12, rc = tid & 4095, r = rc >> 6, c = rc & 63;
    float v = -1e30f;
    if (r < NTOK && c < NTOK) {
      int ih = r / 7, iw = r - ih * 7, jh = c / 7, jw = c - jh * 7;
      v = bias_table[((ih - jh + 6) * 13 + (iw - jw + 6)) * HEADS + h];
    }
    biasM[tid] = v;
  } else {
    int t2 = tid - 65536;
    int mw = t2 >> 12, rc = t2 & 4095, r = rc >> 6, c = rc & 63;
    float v = 0.f;
    if (r < NTOK && c < NTOK) {
      int mwR = (mw >> 3) * 7, mwC = (mw & 7) * 7;
      int ih = r / 7, iw = r - ih * 7, jh = c / 7, jw = c - jh * 7;
      int gih = mwR + ih, giw = mwC + iw, gjh = mwR + jh, gjw = mwC + jw;
      int ri = (gih < 49 ? 0 : (gih < 53 ? 1 : 2)) * 3 + (giw < 49 ? 0 : (giw < 53 ? 1 : 2));
      int rj = (gjh < 49 ? 0 : (gjh < 53 ? 1 : 2)) * 3 + (gjw < 49 ? 0 : (gjw < 53 ? 1 : 2));
      v = (ri != rj) ? -100.f : 0.f;
    }
    maskT[t2] = v;
  }
}

// ---------------- GEMM: C[M][Nn] = A[M][K] @ Bt[Nn][K]^T + bias ----------------
template<int OUT_F32>
__global__ __launch_bounds__(256, 3) void k_gemm(const u16* __restrict__ A,
                                                 const u16* __restrict__ Bt,
                                                 const float* __restrict__ bias,
                                                 void* __restrict__ Cp,
                                                 int M, int Nn, int K, int nbn) {
  __shared__ u16 smem[17408];                  // loop: 2 x A[128x64] (32 KB); epilogue: 128x136
  const int t   = threadIdx.x;
  // T1: XCD-contiguous bijective swizzle (gridDim.x % 8 == 0 for both GEMMs)
  const int q8  = gridDim.x >> 3;
  const int bid = (blockIdx.x & 7) * q8 + (blockIdx.x >> 3);
  const int cb  = bid % nbn, rb = bid / nbn;   // consecutive logical bids share rb
  const int row0 = rb << 7, col0 = cb << 7;
  const int lane = t & 63, w = t >> 6;
  const int wr = (w >> 1) << 6, wc = (w & 1) << 6;
  const int lm = lane & 15, lk = lane >> 4;

  const f32x4 fz = {0.f, 0.f, 0.f, 0.f};
  f32x4 acc[4][4];
#pragma unroll
  for (int i = 0; i < 4; i++)
#pragma unroll
    for (int j = 0; j < 4; j++) acc[i][j] = fz;

  // A staging source-chunk swizzle (loop-invariant): chunk c -> c ^ (row&7)
  int gr[4], gc[4], gdb[4];
#pragma unroll
  for (int i = 0; i < 4; ++i) {
    int q = (i << 8) + t;
    gr[i]  = q >> 3;
    gc[i]  = (((q & 7) ^ (gr[i] & 7)) << 3);
    gdb[i] = ((i << 8) + (t & 192)) << 3;      // wave-uniform dest base (u16)
  }
  // A read-side swizzled offsets (loop-invariant)
  int offA[4];
#pragma unroll
  for (int i = 0; i < 4; ++i) {
    int rowA = wr + i * 16 + lm;
    offA[i] = rowA * 64 + ((lk ^ (rowA & 7)) << 3);
  }
  // B direct-from-global per-lane row pointers (L2-resident weight panel)
  const u16* bp[4];
#pragma unroll
  for (int ni = 0; ni < 4; ++ni)
    bp[ni] = Bt + (size_t)(col0 + wc + ni * 16 + lm) * K + lk * 8;

  auto stageA = [&](int p, int kt) {
    const int kb = kt << 6;
    u16* dA = smem + p * 8192;
#pragma unroll
    for (int i = 0; i < 4; ++i)
      gload16(A + (size_t)(row0 + gr[i]) * K + kb + gc[i], dA + gdb[i]);
  };

  const int nk = K >> 6;
  stageA(0, 0);                                 // 4 A-loads in flight
  int p = 0;
  for (int kt = 0; kt < nk; ++kt) {
    const int kb = kt << 6;
    if (kt + 1 < nk) stageA(p ^ 1, kt + 1);     // +4 (A kt+1)
    // B fragments for tile kt: 8 x dwordx4 straight to VGPR (+8)
    bf16x8 b[4][2];
#pragma unroll
    for (int ni = 0; ni < 4; ++ni) {
      b[ni][0] = *(const bf16x8*)(bp[ni] + kb);
      b[ni][1] = *(const bf16x8*)(bp[ni] + kb + 32);
    }
    if (kt + 1 < nk) {
      // 12 newest = A(kt+1) 4 + B(kt) 8 -> everything older (A kt) landed.
      asm volatile("s_waitcnt vmcnt(12)" ::: "memory");
    } else {
      asm volatile("s_waitcnt vmcnt(8)" ::: "memory");   // 8 newest = B(kt)
    }
    __builtin_amdgcn_s_barrier();               // all waves' tile-kt A landed
    asm volatile("" ::: "memory");
    const u16* sA = smem + p * 8192;
    bf16x8 a[4][2];
#pragma unroll
    for (int mi = 0; mi < 4; ++mi) {
      a[mi][0] = *(const bf16x8*)(sA + offA[mi]);
      a[mi][1] = *(const bf16x8*)(sA + (offA[mi] ^ 32));
    }
#pragma unroll
    for (int kk = 0; kk < 2; ++kk)
#pragma unroll
      for (int mi = 0; mi < 4; ++mi)
#pragma unroll
        for (int ni = 0; ni < 4; ++ni)
          acc[mi][ni] = __builtin_amdgcn_mfma_f32_16x16x32_bf16(a[mi][kk], b[ni][kk],
                                                                acc[mi][ni], 0, 0, 0);
    asm volatile("" ::: "memory");
    __builtin_amdgcn_s_barrier();               // A-buf reads done; NO vmcnt drain
    asm volatile("" ::: "memory");
    p ^= 1;
  }

  if constexpr (!OUT_F32) {
    // bf16 out: stage whole 128x128 tile in LDS (stride 136), coalesced copy
#pragma unroll
    for (int mi = 0; mi < 4; ++mi)
#pragma unroll
      for (int ni = 0; ni < 4; ++ni) {
        int col = wc + ni * 16 + lm;
        float bv = bias[col0 + col];
#pragma unroll
        for (int r = 0; r < 4; ++r)
          smem[(wr + mi * 16 + lk * 4 + r) * 136 + col] = f2bf(acc[mi][ni][r] + bv);
      }
    __syncthreads();
    const int rr = t >> 1, seg = t & 1;
    u16* dst = (u16*)Cp + (size_t)(row0 + rr) * Nn + col0 + seg * 64;
    const u16* src = smem + rr * 136 + seg * 64;
#pragma unroll
    for (int i = 0; i < 8; ++i)
      *(int4*)(dst + i * 8) = *(const int4*)(src + i * 8);
  } else {
    float* smf = (float*)smem;
    for (int half = 0; half < 2; ++half) {
      __syncthreads();
      if ((w >> 1) == half) {
#pragma unroll
        for (int mi = 0; mi < 4; ++mi)
#pragma unroll
          for (int ni = 0; ni < 4; ++ni) {
            int col = wc + ni * 16 + lm;
            float bv = bias[col0 + col];
#pragma unroll
            for (int r = 0; r < 4; ++r)
              smf[(mi * 16 + lk * 4 + r) * 132 + col] = acc[mi][ni][r] + bv;
          }
      }
      __syncthreads();
      const int rr = t >> 2, seg = t & 3;
      float* dst = (float*)Cp + (size_t)(row0 + half * 64 + rr) * Nn + col0 + seg * 32;
      const float* src = smf + rr * 132 + seg * 32;
#pragma unroll
      for (int i = 0; i < 8; ++i)
        *(float4*)(dst + i * 4) = *(const float4*)(src + i * 4);
    }
  }
}

// ---------------- fused window attention ----------------
// Block = window, 4 waves; wave wv handles heads 4wv..4wv+3 sequentially.
// Swapped QK^T (mfma(K,Q)): lane (lm,lk) holds S[q=lm+16mi][k=ni*16+lk*4+r];
// softmax row lives in 4 lanes {lm,+16,+32,+48} -> 2-shuffle reduce.
// bias+mask enter as the MFMA C operand. All LDS wave-private: NO barriers.
__global__ __launch_bounds__(256) void k_attn(const u16* __restrict__ qkv,
                                              const float* __restrict__ biasM,
                                              const float* __restrict__ maskT,
                                              u16* __restrict__ aout) {
  __shared__ u16 sm[4 * 3264];      // per wave: sV 32x68 (V^T) + sP 16x68
  const int wdx = blockIdx.x;       // window 0..2047
  const int mw  = wdx & 63;
  const int t   = threadIdx.x;
  const int wv  = t >> 6;
  const int l   = t & 63;
  const int lm  = l & 15, lk = l >> 4;
  const size_t tb = (size_t)wdx * NTOK;
  const u16* base = qkv + tb * 1536;
  u16* sV = sm + wv * 3264;
  u16* sP = sV + 2176;

  const int4  iz = make_int4(0, 0, 0, 0);
  const f32x4 fz = {0.f, 0.f, 0.f, 0.f};
  const float* mT = maskT + (mw << 12);

  for (int hh = 0; hh < 4; ++hh) {
    const int h = (wv << 2) + hh;

    // stage V^T (wave-private): lane l = token row; 32 d-values scattered
    {
      int4 vv[4] = {iz, iz, iz, iz};
      if (l < NTOK) {
        const u16* vp = base + (size_t)l * 1536 + 1024 + h * 32;
#pragma unroll
        for (int i = 0; i < 4; ++i) vv[i] = *(const int4*)(vp + i * 8);
      }
      const u16* u = (const u16*)vv;
#pragma unroll
      for (int d = 0; d < 32; ++d) sV[d * 68 + l] = u[d];
    }

    // K fragments (all 64 k-rows)
    bf16x8 kf[4];
#pragma unroll
    for (int ni = 0; ni < 4; ++ni) {
      int krow = ni * 16 + lm;
      int4 ki = (krow < NTOK)
        ? *(const int4*)(base + (size_t)krow * 1536 + 512 + h * 32 + lk * 8) : iz;
      kf[ni] = __builtin_bit_cast(bf16x8, ki);
    }

    // V^T fragments (after same-wave LDS writes; lgkmcnt ordering is automatic)
    bf16x8 vb[2][2];
#pragma unroll
    for (int kt = 0; kt < 2; ++kt)
#pragma unroll
      for (int df = 0; df < 2; ++df)
        vb[kt][df] = *(const bf16x8*)(sV + (df * 16 + lm) * 68 + kt * 32 + lk * 8);

    const float* bM = biasM + (h << 12);

#pragma unroll
    for (int mi = 0; mi < 4; ++mi) {
      const int qrow = mi * 16 + lm;
      int4 qi = (qrow < NTOK)
        ? *(const int4*)(base + (size_t)qrow * 1536 + h * 32 + lk * 8) : iz;
      bf16x8 qf = __builtin_bit_cast(bf16x8, qi);

      f32x4 st[4];
#pragma unroll
      for (int ni = 0; ni < 4; ++ni) {
        const int o4 = (qrow << 6) + ni * 16 + lk * 4;
        float4 b4 = *(const float4*)(bM + o4);
        float4 m4 = *(const float4*)(mT + o4);
        f32x4 ci = {b4.x + m4.x, b4.y + m4.y, b4.z + m4.z, b4.w + m4.w};
        st[ni] = __builtin_amdgcn_mfma_f32_16x16x32_bf16(kf[ni], qf, ci, 0, 0, 0);
      }

      // lane-local softmax row (4-lane group reduce)
      float mx = -3e38f;
#pragma unroll
      for (int ni = 0; ni < 4; ++ni)
#pragma unroll
        for (int r = 0; r < 4; ++r) mx = fmaxf(mx, st[ni][r]);
      mx = fmaxf(mx, __shfl_xor(mx, 16, 64));
      mx = fmaxf(mx, __shfl_xor(mx, 32, 64));
      float sum = 0.f;
#pragma unroll
      for (int ni = 0; ni < 4; ++ni)
#pragma unroll
        for (int r = 0; r < 4; ++r) {
          float p = __expf(st[ni][r] - mx);
          st[ni][r] = p;
          sum += p;
        }
      sum += __shfl_xor(sum, 16, 64);
      sum += __shfl_xor(sum, 32, 64);
      const float rinv = __builtin_amdgcn_rcpf(sum);

      // normalized P -> wave-private LDS (b64 writes, k-contiguous)
#pragma unroll
      for (int ni = 0; ni < 4; ++ni) {
        u16 pk[4] = {f2bf(st[ni][0] * rinv), f2bf(st[ni][1] * rinv),
                     f2bf(st[ni][2] * rinv), f2bf(st[ni][3] * rinv)};
        *(int2*)(sP + lm * 68 + ni * 16 + lk * 4) = *(const int2*)pk;
      }

      // O = P @ V^T-frag: D[q=lk*4+r][d=df*16+lm]
      f32x4 o0 = fz, o1 = fz;
#pragma unroll
      for (int kt = 0; kt < 2; ++kt) {
        bf16x8 pa = *(const bf16x8*)(sP + lm * 68 + kt * 32 + lk * 8);
        o0 = __builtin_amdgcn_mfma_f32_16x16x32_bf16(pa, vb[kt][0], o0, 0, 0, 0);
        o1 = __builtin_amdgcn_mfma_f32_16x16x32_bf16(pa, vb[kt][1], o1, 0, 0, 0);
      }

#pragma unroll
      for (int r = 0; r < 4; ++r) {
        int tok = mi * 16 + lk * 4 + r;
        if (tok < NTOK) {
          size_t ob = (tb + tok) * CH + h * 32;
          aout[ob + lm]      = f2bf(o0[r]);
          aout[ob + 16 + lm] = f2bf(o1[r]);
        }
      }
    }
  }
}

extern "C" void kernel_launch(void* const* d_in, const int* in_sizes, int n_in,
                              void* d_out, int out_size, void* d_ws, size_t ws_size,
                              hipStream_t stream) {
  const float* x      = (const float*)d_in[0];
  const float* qkv_b  = (const float*)d_in[2];
  const float* proj_b = (const float*)d_in[4];
  const float* btab   = (const float*)d_in[5];

  char* ws   = (char*)d_ws;
  u16* Wt    = (u16*)ws;                                  // 1,572,864 B
  u16* Pt    = (u16*)(ws + 1572864);                      //   524,288 B
  u16* qkv   = (u16*)(ws + 2097152);                      // 308,281,344 B
  u16* aout  = (u16*)(ws + 2097152 + 308281344ull);       // 102,760,448 B (aliased xb)
  u16* xb    = aout;                                      // dead once attn writes aout
  float* biasM = (float*)(ws + 2097152 + 308281344ull + 102760448ull);  // 262,144 B
  float* maskT = biasM + 65536;                           // 1,048,576 B
  float* bias2 = maskT + 262144;                          //     6,144 B
  float* out = (float*)d_out;

  k_wprep<<<4096, 256, 0, stream>>>((const float*)d_in[1], (const float*)d_in[3],
                                    qkv_b, Wt, Pt, bias2);
  k_xcast<<<25088, 256, 0, stream>>>(x, xb);
  k_tabs<<<1280, 256, 0, stream>>>(btab, biasM, maskT);
  k_gemm<0><<<784 * 12, 256, 0, stream>>>(xb, Wt, bias2, (void*)qkv, 100352, 1536, 512, 12);
  k_attn<<<2048, 256, 0, stream>>>(qkv, biasM, maskT, aout);
  k_gemm<1><<<784 * 4, 256, 0, stream>>>(aout, Pt, proj_b, (void*)out, 100352, 512, 512, 4);
}

// Round 12
// 709.921 us; speedup vs baseline: 1.0611x; 1.0611x over previous
//
#include <hip/hip_runtime.h>
#include <hip/hip_bf16.h>
#include <stdint.h>

// WindowAttention (Swin, shifted): x[2048,49,512] f32 -> out[2048,49,512] f32
// Pipeline:
//   k_wprep: TILED cast+transpose weights to bf16 [N][K] (32x32 LDS tiles);
//            q-cols pre-scaled by 32^-0.5
//   k_xcast: x f32 -> bf16 (into aout region, dead until attn writes it)
//   k_tabs : bias[h][64][64], mask[mw][64][64] f32 tables + bias2
//   k_gemm<0>: qkv = xb @ Wt^T + bias2     (bf16 out, 158 GF)  [R10 structure]
//   k_attn : block=window, 4 waves; swapped QK^T lane-local softmax;
//            batched K/Q issue + depth-1 V prefetch (T14); no barriers.
//   k_gemm<1>: out = aout @ Pt^T + proj_b  (f32 out, 53 GF)
// k_gemm: 128x128 tile, 4 waves, BK=64, 64KB LDS double-buffer (2 blocks/CU),
// COUNTED-vmcnt pipeline (vmcnt(8), never drained in loop), T2 XOR-swizzle,
// T1 XCD-contiguous block swizzle, LDS-staged coalesced epilogue.

#define HEADS 16
#define NTOK  49
#define CH    512

typedef float  f32x4  __attribute__((ext_vector_type(4)));
typedef __bf16 bf16x8 __attribute__((ext_vector_type(8)));
typedef unsigned short u16;
typedef unsigned int   u32;

__device__ __forceinline__ u16 f2bf(float f) {
  return __builtin_bit_cast(u16, (__bf16)f);   // native v_cvt, RNE
}

__device__ __forceinline__ void gload16(const u16* g, u16* l) {
  __builtin_amdgcn_global_load_lds(
      (const __attribute__((address_space(1))) u32*)g,
      (__attribute__((address_space(3))) u32*)l, 16, 0, 0);
}

// ---------------- weight prep: tiled 32x32 transpose, both sides coalesced ----------------
__global__ __launch_bounds__(256) void k_wprep(const float* __restrict__ qkv_w,
                                               const float* __restrict__ proj_w,
                                               u16* __restrict__ Wt, u16* __restrict__ Pt) {
  __shared__ float tile[32][33];
  const float sc = 0.17677669529663687f;       // 32^-0.5
  int b = blockIdx.x;
  const float* src; u16* dst; int ld, tk, tn, scaleN;
  if (b < 768) { src = qkv_w; dst = Wt; ld = 1536; tk = (b / 48) * 32; tn = (b % 48) * 32; scaleN = 512; }
  else { b -= 768; src = proj_w; dst = Pt; ld = 512; tk = (b / 16) * 32; tn = (b % 16) * 32; scaleN = 0; }
  const int c = threadIdx.x & 31, r0 = threadIdx.x >> 5;
#pragma unroll
  for (int i = 0; i < 4; ++i) {
    int r = r0 + i * 8;
    tile[r][c] = src[(size_t)(tk + r) * ld + tn + c];   // coalesced read
  }
  __syncthreads();
#pragma unroll
  for (int i = 0; i < 4; ++i) {
    int r = r0 + i * 8;
    float v = tile[c][r];                                // transposed, pad-33 conflict-free
    if (tn + r < scaleN) v *= sc;
    dst[(size_t)(tn + r) * 512 + tk + c] = f2bf(v);      // coalesced write
  }
}

// ---------------- x cast: f32 -> bf16, 8 elems/thread ----------------
__global__ __launch_bounds__(256) void k_xcast(const float* __restrict__ x,
                                               u16* __restrict__ xb) {
  int tid = blockIdx.x * 256 + threadIdx.x;
  const float4* xv = (const float4*)x;
  float4 a = xv[tid * 2], b = xv[tid * 2 + 1];
  u16 o[8] = {f2bf(a.x), f2bf(a.y), f2bf(a.z), f2bf(a.w),
              f2bf(b.x), f2bf(b.y), f2bf(b.z), f2bf(b.w)};
  ((int4*)xb)[tid] = *(const int4*)o;
}

// ---------------- bias/mask tables + bias2 ----------------
__global__ __launch_bounds__(256) void k_tabs(const float* __restrict__ bias_table,
                                              const float* __restrict__ qkv_b,
                                              float* __restrict__ biasM,
                                              float* __restrict__ maskT,
                                              float* __restrict__ bias2) {
  const float sc = 0.17677669529663687f;
  int tid = blockIdx.x * 256 + threadIdx.x;
  if (tid < 1536) bias2[tid] = qkv_b[tid] * (tid < 512 ? sc : 1.f);
  if (tid < 16 * 4096) {
    int h = tid >> 12, rc = tid & 4095, r = rc >> 6, c = rc & 63;
    float v = -1e30f;
    if (r < NTOK && c < NTOK) {
      int ih = r / 7, iw = r - ih * 7, jh = c / 7, jw = c - jh * 7;
      v = bias_table[((ih - jh + 6) * 13 + (iw - jw + 6)) * HEADS + h];
    }
    biasM[tid] = v;
  } else {
    int t2 = tid - 65536;
    int mw = t2 >> 12, rc = t2 & 4095, r = rc >> 6, c = rc & 63;
    float v = 0.f;
    if (r < NTOK && c < NTOK) {
      int mwR = (mw >> 3) * 7, mwC = (mw & 7) * 7;
      int ih = r / 7, iw = r - ih * 7, jh = c / 7, jw = c - jh * 7;
      int gih = mwR + ih, giw = mwC + iw, gjh = mwR + jh, gjw = mwC + jw;
      int ri = (gih < 49 ? 0 : (gih < 53 ? 1 : 2)) * 3 + (giw < 49 ? 0 : (giw < 53 ? 1 : 2));
      int rj = (gjh < 49 ? 0 : (gjh < 53 ? 1 : 2)) * 3 + (gjw < 49 ? 0 : (gjw < 53 ? 1 : 2));
      v = (ri != rj) ? -100.f : 0.f;
    }
    maskT[t2] = v;
  }
}

// ---------------- GEMM: C[M][Nn] = A[M][K] @ Bt[Nn][K]^T + bias  (R10 exact) ----------------
template<int OUT_F32>
__global__ __launch_bounds__(256, 2) void k_gemm(const u16* __restrict__ A,
                                                 const u16* __restrict__ Bt,
                                                 const float* __restrict__ bias,
                                                 void* __restrict__ Cp,
                                                 int M, int Nn, int K, int nbn) {
  __shared__ u16 smem[2 * 16384];              // 64 KiB: 2 x {A 128x64 | B 128x64}
  const int t   = threadIdx.x;
  const int q8  = gridDim.x >> 3;
  const int bid = (blockIdx.x & 7) * q8 + (blockIdx.x >> 3);
  const int cb  = bid % nbn, rb = bid / nbn;
  const int row0 = rb << 7, col0 = cb << 7;
  const int lane = t & 63, w = t >> 6;
  const int wr = (w >> 1) << 6, wc = (w & 1) << 6;
  const int lm = lane & 15, lk = lane >> 4;

  const f32x4 fz = {0.f, 0.f, 0.f, 0.f};
  f32x4 acc[4][4];
#pragma unroll
  for (int i = 0; i < 4; i++)
#pragma unroll
    for (int j = 0; j < 4; j++) acc[i][j] = fz;

  int gr[4], gc[4], gdb[4];
#pragma unroll
  for (int i = 0; i < 4; ++i) {
    int q = (i << 8) + t;
    gr[i]  = q >> 3;
    gc[i]  = (((q & 7) ^ (gr[i] & 7)) << 3);
    gdb[i] = ((i << 8) + (t & 192)) << 3;
  }
  int offA[4], offB[4];
#pragma unroll
  for (int i = 0; i < 4; ++i) {
    int rowA = wr + i * 16 + lm;
    offA[i] = rowA * 64 + ((lk ^ (rowA & 7)) << 3);
    int rowB = wc + i * 16 + lm;
    offB[i] = rowB * 64 + ((lk ^ (rowB & 7)) << 3);
  }

  auto stage = [&](int p, int kt) {
    const int kb = kt << 6;
    u16* dA = smem + p * 16384;
    u16* dB = dA + 8192;
#pragma unroll
    for (int i = 0; i < 4; ++i) {
      gload16(A  + (size_t)(row0 + gr[i]) * K + kb + gc[i], dA + gdb[i]);
      gload16(Bt + (size_t)(col0 + gr[i]) * K + kb + gc[i], dB + gdb[i]);
    }
  };

  const int nk = K >> 6;
  stage(0, 0);
  int p = 0;
  for (int kt = 0; kt < nk; ++kt) {
    if (kt + 1 < nk) {
      stage(p ^ 1, kt + 1);
      asm volatile("s_waitcnt vmcnt(8)" ::: "memory");
    } else {
      asm volatile("s_waitcnt vmcnt(0)" ::: "memory");
    }
    __builtin_amdgcn_s_barrier();
    asm volatile("" ::: "memory");
    const u16* sA = smem + p * 16384;
    const u16* sB = sA + 8192;
    bf16x8 a[4][2], b[4][2];
#pragma unroll
    for (int mi = 0; mi < 4; ++mi) {
      a[mi][0] = *(const bf16x8*)(sA + offA[mi]);
      a[mi][1] = *(const bf16x8*)(sA + (offA[mi] ^ 32));
    }
#pragma unroll
    for (int ni = 0; ni < 4; ++ni) {
      b[ni][0] = *(const bf16x8*)(sB + offB[ni]);
      b[ni][1] = *(const bf16x8*)(sB + (offB[ni] ^ 32));
    }
#pragma unroll
    for (int kk = 0; kk < 2; ++kk)
#pragma unroll
      for (int mi = 0; mi < 4; ++mi)
#pragma unroll
        for (int ni = 0; ni < 4; ++ni)
          acc[mi][ni] = __builtin_amdgcn_mfma_f32_16x16x32_bf16(a[mi][kk], b[ni][kk],
                                                                acc[mi][ni], 0, 0, 0);
    asm volatile("" ::: "memory");
    __builtin_amdgcn_s_barrier();
    asm volatile("" ::: "memory");
    p ^= 1;
  }

  if constexpr (!OUT_F32) {
#pragma unroll
    for (int mi = 0; mi < 4; ++mi)
#pragma unroll
      for (int ni = 0; ni < 4; ++ni) {
        int col = wc + ni * 16 + lm;
        float bv = bias[col0 + col];
#pragma unroll
        for (int r = 0; r < 4; ++r)
          smem[(wr + mi * 16 + lk * 4 + r) * 136 + col] = f2bf(acc[mi][ni][r] + bv);
      }
    __syncthreads();
    const int rr = t >> 1, seg = t & 1;
    u16* dst = (u16*)Cp + (size_t)(row0 + rr) * Nn + col0 + seg * 64;
    const u16* src = smem + rr * 136 + seg * 64;
#pragma unroll
    for (int i = 0; i < 8; ++i)
      *(int4*)(dst + i * 8) = *(const int4*)(src + i * 8);
  } else {
    float* smf = (float*)smem;
    for (int half = 0; half < 2; ++half) {
      __syncthreads();
      if ((w >> 1) == half) {
#pragma unroll
        for (int mi = 0; mi < 4; ++mi)
#pragma unroll
          for (int ni = 0; ni < 4; ++ni) {
            int col = wc + ni * 16 + lm;
            float bv = bias[col0 + col];
#pragma unroll
            for (int r = 0; r < 4; ++r)
              smf[(mi * 16 + lk * 4 + r) * 132 + col] = acc[mi][ni][r] + bv;
          }
      }
      __syncthreads();
      const int rr = t >> 2, seg = t & 3;
      float* dst = (float*)Cp + (size_t)(row0 + half * 64 + rr) * Nn + col0 + seg * 32;
      const float* src = smf + rr * 132 + seg * 32;
#pragma unroll
      for (int i = 0; i < 8; ++i)
        *(float4*)(dst + i * 4) = *(const float4*)(src + i * 4);
    }
  }
}

// ---------------- fused window attention ----------------
// Block = window, 4 waves; wave wv handles heads 4wv..4wv+3 sequentially.
// Swapped QK^T (mfma(K,Q)): lane (lm,lk) holds S[q=lm+16mi][k=ni*16+lk*4+r].
// Per head: batch-issue K+Q loads first (latency hides under V's LDS round
// trip), then depth-1 prefetch of next head's V (T14). Named register sets
// vvA/vvB with statically-unrolled calls (no runtime-indexed arrays).
__global__ __launch_bounds__(256) void k_attn(const u16* __restrict__ qkv,
                                              const float* __restrict__ biasM,
                                              const float* __restrict__ maskT,
                                              u16* __restrict__ aout) {
  __shared__ u16 sm[4 * 3264];      // per wave: sV 32x68 (V^T) + sP 16x68
  const int wdx = blockIdx.x;       // window 0..2047
  const int mw  = wdx & 63;
  const int t   = threadIdx.x;
  const int wv  = t >> 6;
  const int l   = t & 63;
  const int lm  = l & 15, lk = l >> 4;
  const size_t tb = (size_t)wdx * NTOK;
  const u16* base = qkv + tb * 1536;
  u16* sV = sm + wv * 3264;
  u16* sP = sV + 2176;

  const int4  iz = make_int4(0, 0, 0, 0);
  const f32x4 fz = {0.f, 0.f, 0.f, 0.f};
  const float* mT = maskT + (mw << 12);
  const u16* vbase = base + (size_t)l * 1536 + 1024;

  int4 vvA[4], vvB[4];

  auto loadV = [&](int h, int4 (&dst)[4]) {
    const u16* vp = vbase + h * 32;
#pragma unroll
    for (int i = 0; i < 4; ++i)
      dst[i] = (l < NTOK) ? *(const int4*)(vp + i * 8) : iz;
  };

  auto headBody = [&](int hh, const int4 (&vcur)[4], int4 (&vnext)[4]) {
    const int h = (wv << 2) + hh;

    // batch-issue K (4) and Q (4) loads up front -- 8 in flight
    bf16x8 kf[4];
#pragma unroll
    for (int ni = 0; ni < 4; ++ni) {
      int krow = ni * 16 + lm;
      int4 ki = (krow < NTOK)
        ? *(const int4*)(base + (size_t)krow * 1536 + 512 + h * 32 + lk * 8) : iz;
      kf[ni] = __builtin_bit_cast(bf16x8, ki);
    }
    int4 qi[4];
#pragma unroll
    for (int mi = 0; mi < 4; ++mi) {
      int qrow = mi * 16 + lm;
      qi[mi] = (qrow < NTOK)
        ? *(const int4*)(base + (size_t)qrow * 1536 + h * 32 + lk * 8) : iz;
    }

    // stage V^T from prefetched regs: sV[d][n], row d = contiguous lane writes
    {
      const u16* u = (const u16*)vcur;
#pragma unroll
      for (int d = 0; d < 32; ++d) sV[d * 68 + l] = u[d];
    }
    // depth-1 prefetch: next head's V flies during this head's compute
    if (hh < 3) loadV(h + 1, vnext);

    // V^T fragments (same-wave LDS write->read ordered by lgkmcnt)
    bf16x8 vb[2][2];
#pragma unroll
    for (int kt = 0; kt < 2; ++kt)
#pragma unroll
      for (int df = 0; df < 2; ++df)
        vb[kt][df] = *(const bf16x8*)(sV + (df * 16 + lm) * 68 + kt * 32 + lk * 8);

    const float* bM = biasM + (h << 12);

#pragma unroll
    for (int mi = 0; mi < 4; ++mi) {
      const int qrow = mi * 16 + lm;
      bf16x8 qf = __builtin_bit_cast(bf16x8, qi[mi]);

      f32x4 st[4];
#pragma unroll
      for (int ni = 0; ni < 4; ++ni) {
        const int o4 = (qrow << 6) + ni * 16 + lk * 4;
        float4 b4 = *(const float4*)(bM + o4);
        float4 m4 = *(const float4*)(mT + o4);
        f32x4 ci = {b4.x + m4.x, b4.y + m4.y, b4.z + m4.z, b4.w + m4.w};
        st[ni] = __builtin_amdgcn_mfma_f32_16x16x32_bf16(kf[ni], qf, ci, 0, 0, 0);
      }

      float mx = -3e38f;
#pragma unroll
      for (int ni = 0; ni < 4; ++ni)
#pragma unroll
        for (int r = 0; r < 4; ++r) mx = fmaxf(mx, st[ni][r]);
      mx = fmaxf(mx, __shfl_xor(mx, 16, 64));
      mx = fmaxf(mx, __shfl_xor(mx, 32, 64));
      float sum = 0.f;
#pragma unroll
      for (int ni = 0; ni < 4; ++ni)
#pragma unroll
        for (int r = 0; r < 4; ++r) {
          float pv = __expf(st[ni][r] - mx);
          st[ni][r] = pv;
          sum += pv;
        }
      sum += __shfl_xor(sum, 16, 64);
      sum += __shfl_xor(sum, 32, 64);
      const float rinv = __builtin_amdgcn_rcpf(sum);

#pragma unroll
      for (int ni = 0; ni < 4; ++ni) {
        u16 pk[4] = {f2bf(st[ni][0] * rinv), f2bf(st[ni][1] * rinv),
                     f2bf(st[ni][2] * rinv), f2bf(st[ni][3] * rinv)};
        *(int2*)(sP + lm * 68 + ni * 16 + lk * 4) = *(const int2*)pk;
      }

      f32x4 o0 = fz, o1 = fz;
#pragma unroll
      for (int kt = 0; kt < 2; ++kt) {
        bf16x8 pa = *(const bf16x8*)(sP + lm * 68 + kt * 32 + lk * 8);
        o0 = __builtin_amdgcn_mfma_f32_16x16x32_bf16(pa, vb[kt][0], o0, 0, 0, 0);
        o1 = __builtin_amdgcn_mfma_f32_16x16x32_bf16(pa, vb[kt][1], o1, 0, 0, 0);
      }

#pragma unroll
      for (int r = 0; r < 4; ++r) {
        int tok = mi * 16 + lk * 4 + r;
        if (tok < NTOK) {
          size_t ob = (tb + tok) * CH + h * 32;
          aout[ob + lm]      = f2bf(o0[r]);
          aout[ob + 16 + lm] = f2bf(o1[r]);
        }
      }
    }
  };

  loadV(wv << 2, vvA);
  headBody(0, vvA, vvB);
  headBody(1, vvB, vvA);
  headBody(2, vvA, vvB);
  headBody(3, vvB, vvA);
}

extern "C" void kernel_launch(void* const* d_in, const int* in_sizes, int n_in,
                              void* d_out, int out_size, void* d_ws, size_t ws_size,
                              hipStream_t stream) {
  const float* x      = (const float*)d_in[0];
  const float* qkv_b  = (const float*)d_in[2];
  const float* proj_b = (const float*)d_in[4];
  const float* btab   = (const float*)d_in[5];

  char* ws   = (char*)d_ws;
  u16* Wt    = (u16*)ws;                                  // 1,572,864 B
  u16* Pt    = (u16*)(ws + 1572864);                      //   524,288 B
  u16* qkv   = (u16*)(ws + 2097152);                      // 308,281,344 B
  u16* aout  = (u16*)(ws + 2097152 + 308281344ull);       // 102,760,448 B (aliased xb)
  u16* xb    = aout;                                      // dead once attn writes aout
  float* biasM = (float*)(ws + 2097152 + 308281344ull + 102760448ull);  // 262,144 B
  float* maskT = biasM + 65536;                           // 1,048,576 B
  float* bias2 = maskT + 262144;                          //     6,144 B
  float* out = (float*)d_out;

  k_wprep<<<1024, 256, 0, stream>>>((const float*)d_in[1], (const float*)d_in[3], Wt, Pt);
  k_xcast<<<25088, 256, 0, stream>>>(x, xb);
  k_tabs<<<1280, 256, 0, stream>>>(btab, qkv_b, biasM, maskT, bias2);
  k_gemm<0><<<784 * 12, 256, 0, stream>>>(xb, Wt, bias2, (void*)qkv, 100352, 1536, 512, 12);
  k_attn<<<2048, 256, 0, stream>>>(qkv, biasM, maskT, aout);
  k_gemm<1><<<784 * 4, 256, 0, stream>>>(aout, Pt, proj_b, (void*)out, 100352, 512, 512, 4);
}

// Round 13
// 598.200 us; speedup vs baseline: 1.2592x; 1.1868x over previous
//
#include <hip/hip_runtime.h>
#include <hip/hip_bf16.h>
#include <stdint.h>

// WindowAttention (Swin, shifted): x[2048,49,512] f32 -> out[2048,49,512] f32
// Pipeline:
//   k_wprep: TILED cast+transpose weights to bf16 [N][K] (32x32 LDS tiles);
//            q-cols pre-scaled by 32^-0.5
//   k_xcast: x f32 -> bf16 (into aout region, dead until attn writes it)
//   k_tabs : bias[h][64][64], mask[mw][64][64] f32 tables + bias2
//   k_gemm<0>: qkv = xb @ Wt^T + bias2     (bf16 out, 158 GF)
//   k_attn : block=window, 4 waves; wave wv does heads 4wv..4wv+3 sequentially;
//            swapped QK^T lane-local softmax (R10 structure -- VGPR-lean,
//            occupancy-preserving; R12's reg-prefetch variant REVERTED: it
//            doubled VGPR to 144 and halved occupancy -> +177us).
//   k_gemm<1>: out = aout @ Pt^T + proj_b  (f32 out, 53 GF)
// k_gemm: 128x128 tile, 4 waves, BK=64, 64KB LDS double-buffer (2 blocks/CU),
// COUNTED-vmcnt pipeline (vmcnt(8), never drained in loop), T2 XOR-swizzle,
// T1 XCD-contiguous block swizzle, LDS-staged coalesced epilogue.

#define HEADS 16
#define NTOK  49
#define CH    512

typedef float  f32x4  __attribute__((ext_vector_type(4)));
typedef __bf16 bf16x8 __attribute__((ext_vector_type(8)));
typedef unsigned short u16;
typedef unsigned int   u32;

__device__ __forceinline__ u16 f2bf(float f) {
  return __builtin_bit_cast(u16, (__bf16)f);   // native v_cvt, RNE
}

__device__ __forceinline__ void gload16(const u16* g, u16* l) {
  __builtin_amdgcn_global_load_lds(
      (const __attribute__((address_space(1))) u32*)g,
      (__attribute__((address_space(3))) u32*)l, 16, 0, 0);
}

// ---------------- weight prep: tiled 32x32 transpose, both sides coalesced ----------------
__global__ __launch_bounds__(256) void k_wprep(const float* __restrict__ qkv_w,
                                               const float* __restrict__ proj_w,
                                               u16* __restrict__ Wt, u16* __restrict__ Pt) {
  __shared__ float tile[32][33];
  const float sc = 0.17677669529663687f;       // 32^-0.5
  int b = blockIdx.x;
  const float* src; u16* dst; int ld, tk, tn, scaleN;
  if (b < 768) { src = qkv_w; dst = Wt; ld = 1536; tk = (b / 48) * 32; tn = (b % 48) * 32; scaleN = 512; }
  else { b -= 768; src = proj_w; dst = Pt; ld = 512; tk = (b / 16) * 32; tn = (b % 16) * 32; scaleN = 0; }
  const int c = threadIdx.x & 31, r0 = threadIdx.x >> 5;
#pragma unroll
  for (int i = 0; i < 4; ++i) {
    int r = r0 + i * 8;
    tile[r][c] = src[(size_t)(tk + r) * ld + tn + c];   // coalesced read
  }
  __syncthreads();
#pragma unroll
  for (int i = 0; i < 4; ++i) {
    int r = r0 + i * 8;
    float v = tile[c][r];                                // transposed, pad-33 conflict-free
    if (tn + r < scaleN) v *= sc;
    dst[(size_t)(tn + r) * 512 + tk + c] = f2bf(v);      // coalesced write
  }
}

// ---------------- x cast: f32 -> bf16, 8 elems/thread ----------------
__global__ __launch_bounds__(256) void k_xcast(const float* __restrict__ x,
                                               u16* __restrict__ xb) {
  int tid = blockIdx.x * 256 + threadIdx.x;
  const float4* xv = (const float4*)x;
  float4 a = xv[tid * 2], b = xv[tid * 2 + 1];
  u16 o[8] = {f2bf(a.x), f2bf(a.y), f2bf(a.z), f2bf(a.w),
              f2bf(b.x), f2bf(b.y), f2bf(b.z), f2bf(b.w)};
  ((int4*)xb)[tid] = *(const int4*)o;
}

// ---------------- bias/mask tables + bias2 ----------------
__global__ __launch_bounds__(256) void k_tabs(const float* __restrict__ bias_table,
                                              const float* __restrict__ qkv_b,
                                              float* __restrict__ biasM,
                                              float* __restrict__ maskT,
                                              float* __restrict__ bias2) {
  const float sc = 0.17677669529663687f;
  int tid = blockIdx.x * 256 + threadIdx.x;
  if (tid < 1536) bias2[tid] = qkv_b[tid] * (tid < 512 ? sc : 1.f);
  if (tid < 16 * 4096) {
    int h = tid >> 12, rc = tid & 4095, r = rc >> 6, c = rc & 63;
    float v = -1e30f;
    if (r < NTOK && c < NTOK) {
      int ih = r / 7, iw = r - ih * 7, jh = c / 7, jw = c - jh * 7;
      v = bias_table[((ih - jh + 6) * 13 + (iw - jw + 6)) * HEADS + h];
    }
    biasM[tid] = v;
  } else {
    int t2 = tid - 65536;
    int mw = t2 >> 12, rc = t2 & 4095, r = rc >> 6, c = rc & 63;
    float v = 0.f;
    if (r < NTOK && c < NTOK) {
      int mwR = (mw >> 3) * 7, mwC = (mw & 7) * 7;
      int ih = r / 7, iw = r - ih * 7, jh = c / 7, jw = c - jh * 7;
      int gih = mwR + ih, giw = mwC + iw, gjh = mwR + jh, gjw = mwC + jw;
      int ri = (gih < 49 ? 0 : (gih < 53 ? 1 : 2)) * 3 + (giw < 49 ? 0 : (giw < 53 ? 1 : 2));
      int rj = (gjh < 49 ? 0 : (gjh < 53 ? 1 : 2)) * 3 + (gjw < 49 ? 0 : (gjw < 53 ? 1 : 2));
      v = (ri != rj) ? -100.f : 0.f;
    }
    maskT[t2] = v;
  }
}

// ---------------- GEMM: C[M][Nn] = A[M][K] @ Bt[Nn][K]^T + bias  (R10 exact) ----------------
template<int OUT_F32>
__global__ __launch_bounds__(256, 2) void k_gemm(const u16* __restrict__ A,
                                                 const u16* __restrict__ Bt,
                                                 const float* __restrict__ bias,
                                                 void* __restrict__ Cp,
                                                 int M, int Nn, int K, int nbn) {
  __shared__ u16 smem[2 * 16384];              // 64 KiB: 2 x {A 128x64 | B 128x64}
  const int t   = threadIdx.x;
  const int q8  = gridDim.x >> 3;
  const int bid = (blockIdx.x & 7) * q8 + (blockIdx.x >> 3);
  const int cb  = bid % nbn, rb = bid / nbn;
  const int row0 = rb << 7, col0 = cb << 7;
  const int lane = t & 63, w = t >> 6;
  const int wr = (w >> 1) << 6, wc = (w & 1) << 6;
  const int lm = lane & 15, lk = lane >> 4;

  const f32x4 fz = {0.f, 0.f, 0.f, 0.f};
  f32x4 acc[4][4];
#pragma unroll
  for (int i = 0; i < 4; i++)
#pragma unroll
    for (int j = 0; j < 4; j++) acc[i][j] = fz;

  int gr[4], gc[4], gdb[4];
#pragma unroll
  for (int i = 0; i < 4; ++i) {
    int q = (i << 8) + t;
    gr[i]  = q >> 3;
    gc[i]  = (((q & 7) ^ (gr[i] & 7)) << 3);
    gdb[i] = ((i << 8) + (t & 192)) << 3;
  }
  int offA[4], offB[4];
#pragma unroll
  for (int i = 0; i < 4; ++i) {
    int rowA = wr + i * 16 + lm;
    offA[i] = rowA * 64 + ((lk ^ (rowA & 7)) << 3);
    int rowB = wc + i * 16 + lm;
    offB[i] = rowB * 64 + ((lk ^ (rowB & 7)) << 3);
  }

  auto stage = [&](int p, int kt) {
    const int kb = kt << 6;
    u16* dA = smem + p * 16384;
    u16* dB = dA + 8192;
#pragma unroll
    for (int i = 0; i < 4; ++i) {
      gload16(A  + (size_t)(row0 + gr[i]) * K + kb + gc[i], dA + gdb[i]);
      gload16(Bt + (size_t)(col0 + gr[i]) * K + kb + gc[i], dB + gdb[i]);
    }
  };

  const int nk = K >> 6;
  stage(0, 0);
  int p = 0;
  for (int kt = 0; kt < nk; ++kt) {
    if (kt + 1 < nk) {
      stage(p ^ 1, kt + 1);
      asm volatile("s_waitcnt vmcnt(8)" ::: "memory");
    } else {
      asm volatile("s_waitcnt vmcnt(0)" ::: "memory");
    }
    __builtin_amdgcn_s_barrier();
    asm volatile("" ::: "memory");
    const u16* sA = smem + p * 16384;
    const u16* sB = sA + 8192;
    bf16x8 a[4][2], b[4][2];
#pragma unroll
    for (int mi = 0; mi < 4; ++mi) {
      a[mi][0] = *(const bf16x8*)(sA + offA[mi]);
      a[mi][1] = *(const bf16x8*)(sA + (offA[mi] ^ 32));
    }
#pragma unroll
    for (int ni = 0; ni < 4; ++ni) {
      b[ni][0] = *(const bf16x8*)(sB + offB[ni]);
      b[ni][1] = *(const bf16x8*)(sB + (offB[ni] ^ 32));
    }
#pragma unroll
    for (int kk = 0; kk < 2; ++kk)
#pragma unroll
      for (int mi = 0; mi < 4; ++mi)
#pragma unroll
        for (int ni = 0; ni < 4; ++ni)
          acc[mi][ni] = __builtin_amdgcn_mfma_f32_16x16x32_bf16(a[mi][kk], b[ni][kk],
                                                                acc[mi][ni], 0, 0, 0);
    asm volatile("" ::: "memory");
    __builtin_amdgcn_s_barrier();
    asm volatile("" ::: "memory");
    p ^= 1;
  }

  if constexpr (!OUT_F32) {
#pragma unroll
    for (int mi = 0; mi < 4; ++mi)
#pragma unroll
      for (int ni = 0; ni < 4; ++ni) {
        int col = wc + ni * 16 + lm;
        float bv = bias[col0 + col];
#pragma unroll
        for (int r = 0; r < 4; ++r)
          smem[(wr + mi * 16 + lk * 4 + r) * 136 + col] = f2bf(acc[mi][ni][r] + bv);
      }
    __syncthreads();
    const int rr = t >> 1, seg = t & 1;
    u16* dst = (u16*)Cp + (size_t)(row0 + rr) * Nn + col0 + seg * 64;
    const u16* src = smem + rr * 136 + seg * 64;
#pragma unroll
    for (int i = 0; i < 8; ++i)
      *(int4*)(dst + i * 8) = *(const int4*)(src + i * 8);
  } else {
    float* smf = (float*)smem;
    for (int half = 0; half < 2; ++half) {
      __syncthreads();
      if ((w >> 1) == half) {
#pragma unroll
        for (int mi = 0; mi < 4; ++mi)
#pragma unroll
          for (int ni = 0; ni < 4; ++ni) {
            int col = wc + ni * 16 + lm;
            float bv = bias[col0 + col];
#pragma unroll
            for (int r = 0; r < 4; ++r)
              smf[(mi * 16 + lk * 4 + r) * 132 + col] = acc[mi][ni][r] + bv;
          }
      }
      __syncthreads();
      const int rr = t >> 2, seg = t & 3;
      float* dst = (float*)Cp + (size_t)(row0 + half * 64 + rr) * Nn + col0 + seg * 32;
      const float* src = smf + rr * 132 + seg * 32;
#pragma unroll
      for (int i = 0; i < 8; ++i)
        *(float4*)(dst + i * 4) = *(const float4*)(src + i * 4);
    }
  }
}

// ---------------- fused window attention (R10 structure, VGPR-lean) ----------------
// Block = window, 4 waves; wave wv handles heads 4wv..4wv+3 sequentially.
// Swapped QK^T (mfma(K,Q)): lane (lm,lk) holds S[q=lm+16mi][k=ni*16+lk*4+r];
// softmax row lives in 4 lanes {lm,+16,+32,+48} -> 2-shuffle reduce.
// bias+mask enter as the MFMA C operand. All LDS wave-private: NO barriers.
__global__ __launch_bounds__(256) void k_attn(const u16* __restrict__ qkv,
                                              const float* __restrict__ biasM,
                                              const float* __restrict__ maskT,
                                              u16* __restrict__ aout) {
  __shared__ u16 sm[4 * 3264];      // per wave: sV 32x68 (V^T) + sP 16x68
  const int wdx = blockIdx.x;       // window 0..2047
  const int mw  = wdx & 63;
  const int t   = threadIdx.x;
  const int wv  = t >> 6;
  const int l   = t & 63;
  const int lm  = l & 15, lk = l >> 4;
  const size_t tb = (size_t)wdx * NTOK;
  const u16* base = qkv + tb * 1536;
  u16* sV = sm + wv * 3264;
  u16* sP = sV + 2176;

  const int4  iz = make_int4(0, 0, 0, 0);
  const f32x4 fz = {0.f, 0.f, 0.f, 0.f};
  const float* mT = maskT + (mw << 12);

  for (int hh = 0; hh < 4; ++hh) {
    const int h = (wv << 2) + hh;

    // stage V^T (wave-private): lane l = token row; 32 d-values scattered
    {
      int4 vv[4] = {iz, iz, iz, iz};
      if (l < NTOK) {
        const u16* vp = base + (size_t)l * 1536 + 1024 + h * 32;
#pragma unroll
        for (int i = 0; i < 4; ++i) vv[i] = *(const int4*)(vp + i * 8);
      }
      const u16* u = (const u16*)vv;
#pragma unroll
      for (int d = 0; d < 32; ++d) sV[d * 68 + l] = u[d];
    }

    // K fragments (all 64 k-rows)
    bf16x8 kf[4];
#pragma unroll
    for (int ni = 0; ni < 4; ++ni) {
      int krow = ni * 16 + lm;
      int4 ki = (krow < NTOK)
        ? *(const int4*)(base + (size_t)krow * 1536 + 512 + h * 32 + lk * 8) : iz;
      kf[ni] = __builtin_bit_cast(bf16x8, ki);
    }

    // V^T fragments (after same-wave LDS writes; lgkmcnt ordering is automatic)
    bf16x8 vb[2][2];
#pragma unroll
    for (int kt = 0; kt < 2; ++kt)
#pragma unroll
      for (int df = 0; df < 2; ++df)
        vb[kt][df] = *(const bf16x8*)(sV + (df * 16 + lm) * 68 + kt * 32 + lk * 8);

    const float* bM = biasM + (h << 12);

#pragma unroll
    for (int mi = 0; mi < 4; ++mi) {
      const int qrow = mi * 16 + lm;
      int4 qi = (qrow < NTOK)
        ? *(const int4*)(base + (size_t)qrow * 1536 + h * 32 + lk * 8) : iz;
      bf16x8 qf = __builtin_bit_cast(bf16x8, qi);

      f32x4 st[4];
#pragma unroll
      for (int ni = 0; ni < 4; ++ni) {
        const int o4 = (qrow << 6) + ni * 16 + lk * 4;
        float4 b4 = *(const float4*)(bM + o4);
        float4 m4 = *(const float4*)(mT + o4);
        f32x4 ci = {b4.x + m4.x, b4.y + m4.y, b4.z + m4.z, b4.w + m4.w};
        st[ni] = __builtin_amdgcn_mfma_f32_16x16x32_bf16(kf[ni], qf, ci, 0, 0, 0);
      }

      // lane-local softmax row (4-lane group reduce)
      float mx = -3e38f;
#pragma unroll
      for (int ni = 0; ni < 4; ++ni)
#pragma unroll
        for (int r = 0; r < 4; ++r) mx = fmaxf(mx, st[ni][r]);
      mx = fmaxf(mx, __shfl_xor(mx, 16, 64));
      mx = fmaxf(mx, __shfl_xor(mx, 32, 64));
      float sum = 0.f;
#pragma unroll
      for (int ni = 0; ni < 4; ++ni)
#pragma unroll
        for (int r = 0; r < 4; ++r) {
          float p = __expf(st[ni][r] - mx);
          st[ni][r] = p;
          sum += p;
        }
      sum += __shfl_xor(sum, 16, 64);
      sum += __shfl_xor(sum, 32, 64);
      const float rinv = __builtin_amdgcn_rcpf(sum);

      // normalized P -> wave-private LDS (b64 writes, k-contiguous)
#pragma unroll
      for (int ni = 0; ni < 4; ++ni) {
        u16 pk[4] = {f2bf(st[ni][0] * rinv), f2bf(st[ni][1] * rinv),
                     f2bf(st[ni][2] * rinv), f2bf(st[ni][3] * rinv)};
        *(int2*)(sP + lm * 68 + ni * 16 + lk * 4) = *(const int2*)pk;
      }

      // O = P @ V^T-frag: D[q=lk*4+r][d=df*16+lm]
      f32x4 o0 = fz, o1 = fz;
#pragma unroll
      for (int kt = 0; kt < 2; ++kt) {
        bf16x8 pa = *(const bf16x8*)(sP + lm * 68 + kt * 32 + lk * 8);
        o0 = __builtin_amdgcn_mfma_f32_16x16x32_bf16(pa, vb[kt][0], o0, 0, 0, 0);
        o1 = __builtin_amdgcn_mfma_f32_16x16x32_bf16(pa, vb[kt][1], o1, 0, 0, 0);
      }

#pragma unroll
      for (int r = 0; r < 4; ++r) {
        int tok = mi * 16 + lk * 4 + r;
        if (tok < NTOK) {
          size_t ob = (tb + tok) * CH + h * 32;
          aout[ob + lm]      = f2bf(o0[r]);
          aout[ob + 16 + lm] = f2bf(o1[r]);
        }
      }
    }
  }
}

extern "C" void kernel_launch(void* const* d_in, const int* in_sizes, int n_in,
                              void* d_out, int out_size, void* d_ws, size_t ws_size,
                              hipStream_t stream) {
  const float* x      = (const float*)d_in[0];
  const float* qkv_b  = (const float*)d_in[2];
  const float* proj_b = (const float*)d_in[4];
  const float* btab   = (const float*)d_in[5];

  char* ws   = (char*)d_ws;
  u16* Wt    = (u16*)ws;                                  // 1,572,864 B
  u16* Pt    = (u16*)(ws + 1572864);                      //   524,288 B
  u16* qkv   = (u16*)(ws + 2097152);                      // 308,281,344 B
  u16* aout  = (u16*)(ws + 2097152 + 308281344ull);       // 102,760,448 B (aliased xb)
  u16* xb    = aout;                                      // dead once attn writes aout
  float* biasM = (float*)(ws + 2097152 + 308281344ull + 102760448ull);  // 262,144 B
  float* maskT = biasM + 65536;                           // 1,048,576 B
  float* bias2 = maskT + 262144;                          //     6,144 B
  float* out = (float*)d_out;

  k_wprep<<<1024, 256, 0, stream>>>((const float*)d_in[1], (const float*)d_in[3], Wt, Pt);
  k_xcast<<<25088, 256, 0, stream>>>(x, xb);
  k_tabs<<<1280, 256, 0, stream>>>(btab, qkv_b, biasM, maskT, bias2);
  k_gemm<0><<<784 * 12, 256, 0, stream>>>(xb, Wt, bias2, (void*)qkv, 100352, 1536, 512, 12);
  k_attn<<<2048, 256, 0, stream>>>(qkv, biasM, maskT, aout);
  k_gemm<1><<<784 * 4, 256, 0, stream>>>(aout, Pt, proj_b, (void*)out, 100352, 512, 512, 4);
}